// Round 6
// baseline (206.618 us; speedup 1.0000x reference)
//
#include <hip/hip_runtime.h>

#define IMG_W 512
#define IMG_H 512
#define N_IMG 48            // 16 batch * 3 channels
#define TILE_W 64
#define TILE_H 32
#define RAD 5
#define KS 11
#define HALO_H (TILE_H + 2*RAD)   // 42
#define W4 (TILE_W/4)             // 16 col-groups (4 cols each) per tile row

typedef float f32x2 __attribute__((ext_vector_type(2)));

__global__ void ssim_zero_acc(double* acc) {
    if (threadIdx.x == 0) acc[0] = 0.0;
}

// RNE-pack two fp32 into a bf16 pair (values finite, non-NaN here)
__device__ inline unsigned int bf16pair(float a, float b) {
    unsigned int ua = __float_as_uint(a), ub = __float_as_uint(b);
    ua = (ua + 0x7fffu + ((ua >> 16) & 1u)) >> 16;
    ub = (ub + 0x7fffu + ((ub >> 16) & 1u)) >> 16;
    return ua | (ub << 16);
}

// unpack a bf16 pair -> f32x2 (bf16->f32 = shift / mask)
__device__ inline f32x2 up2(unsigned int u) {
    return (f32x2){__uint_as_float(u << 16), __uint_as_float(u & 0xffff0000u)};
}

// packed SSIM for 2 pixels -> scalar partial sum
__device__ inline float ssim2(f32x2 m1, f32x2 m2, f32x2 epp, f32x2 ett, f32x2 ept) {
    const float C1 = 1e-4f, C2 = 9e-4f;
    const f32x2 m1s = m1 * m1, m2s = m2 * m2, m12 = m1 * m2;
    const f32x2 num = (2.f * m12 + C1) * (2.f * (ept - m12) + C2);
    const f32x2 den = (m1s + m2s + C1) * ((epp - m1s) + (ett - m2s) + C2);
    return num.x * __builtin_amdgcn_rcpf(den.x)
         + num.y * __builtin_amdgcn_rcpf(den.y);   // rcp rel err ~1e-7 << 2e-2
}

// NOTE: NO __threadfence / fold-in finalize here. R3/R4 vs R5 isolated it:
// per-block agent-scope fence forces XCD-L2 writeback 6144x/dispatch ->
// halo re-reads fall L2->L3, VALUBusy 45%->15-22%, dur ~280us vs 103us.
// Separate tiny finalize kernel is free (total-main gap is fixed harness cost).
__global__ __launch_bounds__(256, 6)
void ssim_main(const float* __restrict__ pred, const float* __restrict__ targ,
               double* __restrict__ acc)
{
    // All 5 h-conv arrays bf16-packed: 5 x 42 x 16 x 8B = 26880 B
    // -> 6 blocks/CU (161 KB of 160 KiB pool), 24 waves/CU.
    // bf16 RNE noise ~1e-3 abs, zero-mean -> ~3e-5 on final mean (thr 2e-2).
    __shared__ uint2 s_p [HALO_H][W4];
    __shared__ uint2 s_t [HALO_H][W4];
    __shared__ uint2 s_pp[HALO_H][W4];
    __shared__ uint2 s_tt[HALO_H][W4];
    __shared__ uint2 s_pt[HALO_H][W4];
    __shared__ float wave_part[4];

    // Gaussian weights (sigma=1.5, normalized) — fp32 throughout
    float wt[KS];
    {
        float ssum = 0.f;
        #pragma unroll
        for (int i = 0; i < KS; ++i) {
            const float d = (float)(i - RAD);
            wt[i] = expf(-d * d / 4.5f);
            ssum += wt[i];
        }
        #pragma unroll
        for (int i = 0; i < KS; ++i) wt[i] /= ssum;
    }

    const int tid  = threadIdx.x;
    const int col0 = blockIdx.x * TILE_W;
    const int row0 = blockIdx.y * TILE_H;
    const bool edge = (blockIdx.x == 0) || (blockIdx.x == IMG_W / TILE_W - 1);
    const long img = blockIdx.z;
    const float* __restrict__ p = pred + img * (long)(IMG_H * IMG_W);
    const float* __restrict__ t = targ + img * (long)(IMG_H * IMG_W);

    // ---- Phase 1: horizontal 11-tap conv of {p, t, p^2, t^2, p*t} (scalar,
    // proven low-VGPR path; 52 VGPR in R5) ----
    for (int idx = tid; idx < HALO_H * W4; idx += 256) {
        const int rl = idx >> 4;
        const int c4 = idx & 15;
        const int grow = row0 - RAD + rl;
        float oo[5][4];
        #pragma unroll
        for (int a = 0; a < 5; ++a)
            #pragma unroll
            for (int k = 0; k < 4; ++k) oo[a][k] = 0.f;

        if (grow >= 0 && grow < IMG_H) {
            const float* __restrict__ prow = p + (long)grow * IMG_W;
            const float* __restrict__ trow = t + (long)grow * IMG_W;
            const int base = col0 + c4 * 4 - 8;   // 16B aligned; window rp[3..16]

            float rp[20] __attribute__((aligned(16)));
            float rt[20] __attribute__((aligned(16)));
            if (!edge) {
                #pragma unroll
                for (int g = 0; g < 5; ++g) {
                    *(float4*)&rp[4 * g] = *(const float4*)&prow[base + 4 * g];
                    *(float4*)&rt[4 * g] = *(const float4*)&trow[base + 4 * g];
                }
            } else {
                #pragma unroll
                for (int g = 0; g < 5; ++g) {
                    const int gc = base + 4 * g;
                    if (gc >= 0 && gc + 4 <= IMG_W) {
                        *(float4*)&rp[4 * g] = *(const float4*)&prow[gc];
                        *(float4*)&rt[4 * g] = *(const float4*)&trow[gc];
                    } else {
                        #pragma unroll
                        for (int e = 0; e < 4; ++e) {
                            const int c = gc + e;
                            const bool ok = (c >= 0) && (c < IMG_W);
                            rp[4 * g + e] = ok ? prow[c] : 0.f;
                            rt[4 * g + e] = ok ? trow[c] : 0.f;
                        }
                    }
                }
            }
            float vp[14], vt[14], vpp[14], vtt[14], vpt[14];
            #pragma unroll
            for (int i = 0; i < 14; ++i) {
                vp[i]  = rp[i + 3];
                vt[i]  = rt[i + 3];
                vpp[i] = vp[i] * vp[i];
                vtt[i] = vt[i] * vt[i];
                vpt[i] = vp[i] * vt[i];
            }
            #pragma unroll
            for (int j = 0; j < KS; ++j) {
                const float wj = wt[j];
                #pragma unroll
                for (int k = 0; k < 4; ++k) {
                    oo[0][k] += wj * vp [k + j];
                    oo[1][k] += wj * vt [k + j];
                    oo[2][k] += wj * vpp[k + j];
                    oo[3][k] += wj * vtt[k + j];
                    oo[4][k] += wj * vpt[k + j];
                }
            }
        }
        s_p [rl][c4] = make_uint2(bf16pair(oo[0][0], oo[0][1]), bf16pair(oo[0][2], oo[0][3]));
        s_t [rl][c4] = make_uint2(bf16pair(oo[1][0], oo[1][1]), bf16pair(oo[1][2], oo[1][3]));
        s_pp[rl][c4] = make_uint2(bf16pair(oo[2][0], oo[2][1]), bf16pair(oo[2][2], oo[2][3]));
        s_tt[rl][c4] = make_uint2(bf16pair(oo[3][0], oo[3][1]), bf16pair(oo[3][2], oo[3][3]));
        s_pt[rl][c4] = make_uint2(bf16pair(oo[4][0], oo[4][1]), bf16pair(oo[4][2], oo[4][3]));
    }
    __syncthreads();

    // ---- Phase 2: vertical 11-tap conv, 2 rows x 4 cols per thread,
    // packed-f32 accumulation (v_pk_fma_f32) ----
    const int c4  = tid & 15;
    const int rr0 = (tid >> 4) * 2;   // output rows rr0, rr0+1

    f32x2 A0[5][2], A1[5][2];         // [array][col-pair half]
    #pragma unroll
    for (int a = 0; a < 5; ++a) {
        A0[a][0] = (f32x2)(0.f); A0[a][1] = (f32x2)(0.f);
        A1[a][0] = (f32x2)(0.f); A1[a][1] = (f32x2)(0.f);
    }
    #pragma unroll
    for (int j = 0; j < 12; ++j) {
        uint2 u[5];
        u[0] = s_p [rr0 + j][c4];
        u[1] = s_t [rr0 + j][c4];
        u[2] = s_pp[rr0 + j][c4];
        u[3] = s_tt[rr0 + j][c4];
        u[4] = s_pt[rr0 + j][c4];
        f32x2 lo[5], hi[5];
        #pragma unroll
        for (int a = 0; a < 5; ++a) { lo[a] = up2(u[a].x); hi[a] = up2(u[a].y); }
        if (j < 11) {
            const float w = wt[j];
            #pragma unroll
            for (int a = 0; a < 5; ++a) { A0[a][0] += w * lo[a]; A0[a][1] += w * hi[a]; }
        }
        if (j >= 1) {
            const float w = wt[j - 1];
            #pragma unroll
            for (int a = 0; a < 5; ++a) { A1[a][0] += w * lo[a]; A1[a][1] += w * hi[a]; }
        }
    }
    float lsum = 0.f;
    lsum += ssim2(A0[0][0], A0[1][0], A0[2][0], A0[3][0], A0[4][0]);
    lsum += ssim2(A0[0][1], A0[1][1], A0[2][1], A0[3][1], A0[4][1]);
    lsum += ssim2(A1[0][0], A1[1][0], A1[2][0], A1[3][0], A1[4][0]);
    lsum += ssim2(A1[0][1], A1[1][1], A1[2][1], A1[3][1], A1[4][1]);

    // ---- Block reduction -> one double atomic per block ----
    #pragma unroll
    for (int off = 32; off > 0; off >>= 1)
        lsum += __shfl_down(lsum, off, 64);
    const int wave = tid >> 6;
    const int lane = tid & 63;
    if (lane == 0) wave_part[wave] = lsum;
    __syncthreads();
    if (tid == 0) {
        const float bs = wave_part[0] + wave_part[1] + wave_part[2] + wave_part[3];
        atomicAdd(acc, (double)bs);
    }
}

__global__ void ssim_final(const double* __restrict__ acc, float* __restrict__ out) {
    if (threadIdx.x == 0) {
        const double n = (double)N_IMG * (double)IMG_H * (double)IMG_W;
        out[0] = (float)(1.0 - acc[0] / n);
    }
}

extern "C" void kernel_launch(void* const* d_in, const int* in_sizes, int n_in,
                              void* d_out, int out_size, void* d_ws, size_t ws_size,
                              hipStream_t stream) {
    const float* pred = (const float*)d_in[0];
    const float* targ = (const float*)d_in[1];
    float* out  = (float*)d_out;
    double* acc = (double*)d_ws;

    hipLaunchKernelGGL(ssim_zero_acc, dim3(1), dim3(1), 0, stream, acc);
    dim3 grid(IMG_W / TILE_W, IMG_H / TILE_H, N_IMG);   // (8, 16, 48)
    hipLaunchKernelGGL(ssim_main, grid, dim3(256), 0, stream, pred, targ, acc);
    hipLaunchKernelGGL(ssim_final, dim3(1), dim3(1), 0, stream, acc, out);
}

// Round 7
// 193.275 us; speedup vs baseline: 1.0690x; 1.0690x over previous
//
#include <hip/hip_runtime.h>

#define IMG_W 512
#define IMG_H 512
#define N_IMG 48            // 16 batch * 3 channels
#define TILE_W 64
#define TILE_H 32
#define RAD 5
#define KS 11
#define HALO_H (TILE_H + 2*RAD)   // 42
#define W4 (TILE_W/4)             // 16 col-groups (4 cols each) per tile row

typedef float f32x2 __attribute__((ext_vector_type(2)));

__global__ void ssim_zero_acc(double* acc) {
    if (threadIdx.x == 0) acc[0] = 0.0;
}

// RNE-pack two fp32 into a bf16 pair (values finite, non-NaN here)
__device__ inline unsigned int bf16pair(float a, float b) {
    unsigned int ua = __float_as_uint(a), ub = __float_as_uint(b);
    ua = (ua + 0x7fffu + ((ua >> 16) & 1u)) >> 16;
    ub = (ub + 0x7fffu + ((ub >> 16) & 1u)) >> 16;
    return ua | (ub << 16);
}

// unpack a bf16 pair -> f32x2 (bf16->f32 = shift / mask)
__device__ inline f32x2 up2(unsigned int u) {
    return (f32x2){__uint_as_float(u << 16), __uint_as_float(u & 0xffff0000u)};
}

// packed SSIM for 2 pixels -> scalar partial sum
__device__ inline float ssim2(f32x2 m1, f32x2 m2, f32x2 epp, f32x2 ett, f32x2 ept) {
    const float C1 = 1e-4f, C2 = 9e-4f;
    const f32x2 m1s = m1 * m1, m2s = m2 * m2, m12 = m1 * m2;
    const f32x2 num = (2.f * m12 + C1) * (2.f * (ept - m12) + C2);
    const f32x2 den = (m1s + m2s + C1) * ((epp - m1s) + (ett - m2s) + C2);
    return num.x * __builtin_amdgcn_rcpf(den.x)
         + num.y * __builtin_amdgcn_rcpf(den.y);   // rcp rel err ~1e-7 << 2e-2
}

// NOTE 1: NO __threadfence / fold-in finalize. R3/R4 vs R5 isolated it: the
// per-block agent-scope fence forces XCD-L2 writeback 6144x/dispatch ->
// halo re-reads fall L2->L3, VALUBusy collapses, dur ~280us vs 103us.
// NOTE 2: launch_bounds min-waves MUST stay at 4. R6 tried (256,6): allocator
// squeezed to 40 VGPR and spilled ~67MB/dispatch to scratch (WRITE_SIZE
// 0.19->67.8MB), dur 103->120us. LDS (27136B) already permits 6 blocks/CU;
// the HW will co-schedule them as long as natural VGPR alloc <= 80.
__global__ __launch_bounds__(256, 4)
void ssim_main(const float* __restrict__ pred, const float* __restrict__ targ,
               double* __restrict__ acc)
{
    // All 5 h-conv arrays bf16-packed: 5 x 42 x 16 x 8B = 26880 B
    // -> up to 6 blocks/CU, 24 waves/CU.
    // bf16 RNE noise ~1e-3 abs, zero-mean -> ~3e-5 on final mean (thr 2e-2).
    __shared__ uint2 s_p [HALO_H][W4];
    __shared__ uint2 s_t [HALO_H][W4];
    __shared__ uint2 s_pp[HALO_H][W4];
    __shared__ uint2 s_tt[HALO_H][W4];
    __shared__ uint2 s_pt[HALO_H][W4];
    __shared__ float wave_part[4];

    // Gaussian weights (sigma=1.5, normalized) — fp32 throughout
    float wt[KS];
    {
        float ssum = 0.f;
        #pragma unroll
        for (int i = 0; i < KS; ++i) {
            const float d = (float)(i - RAD);
            wt[i] = expf(-d * d / 4.5f);
            ssum += wt[i];
        }
        #pragma unroll
        for (int i = 0; i < KS; ++i) wt[i] /= ssum;
    }

    const int tid  = threadIdx.x;
    const int col0 = blockIdx.x * TILE_W;
    const int row0 = blockIdx.y * TILE_H;
    const bool edge = (blockIdx.x == 0) || (blockIdx.x == IMG_W / TILE_W - 1);
    const long img = blockIdx.z;
    const float* __restrict__ p = pred + img * (long)(IMG_H * IMG_W);
    const float* __restrict__ t = targ + img * (long)(IMG_H * IMG_W);

    // ---- Phase 1: horizontal 11-tap conv of {p, t, p^2, t^2, p*t} ----
    for (int idx = tid; idx < HALO_H * W4; idx += 256) {
        const int rl = idx >> 4;
        const int c4 = idx & 15;
        const int grow = row0 - RAD + rl;
        float oo[5][4];
        #pragma unroll
        for (int a = 0; a < 5; ++a)
            #pragma unroll
            for (int k = 0; k < 4; ++k) oo[a][k] = 0.f;

        if (grow >= 0 && grow < IMG_H) {
            const float* __restrict__ prow = p + (long)grow * IMG_W;
            const float* __restrict__ trow = t + (long)grow * IMG_W;
            const int base = col0 + c4 * 4 - 8;   // 16B aligned; window rp[3..16]

            float rp[20] __attribute__((aligned(16)));
            float rt[20] __attribute__((aligned(16)));
            if (!edge) {
                #pragma unroll
                for (int g = 0; g < 5; ++g) {
                    *(float4*)&rp[4 * g] = *(const float4*)&prow[base + 4 * g];
                    *(float4*)&rt[4 * g] = *(const float4*)&trow[base + 4 * g];
                }
            } else {
                #pragma unroll
                for (int g = 0; g < 5; ++g) {
                    const int gc = base + 4 * g;
                    if (gc >= 0 && gc + 4 <= IMG_W) {
                        *(float4*)&rp[4 * g] = *(const float4*)&prow[gc];
                        *(float4*)&rt[4 * g] = *(const float4*)&trow[gc];
                    } else {
                        #pragma unroll
                        for (int e = 0; e < 4; ++e) {
                            const int c = gc + e;
                            const bool ok = (c >= 0) && (c < IMG_W);
                            rp[4 * g + e] = ok ? prow[c] : 0.f;
                            rt[4 * g + e] = ok ? trow[c] : 0.f;
                        }
                    }
                }
            }
            float vp[14], vt[14], vpp[14], vtt[14], vpt[14];
            #pragma unroll
            for (int i = 0; i < 14; ++i) {
                vp[i]  = rp[i + 3];
                vt[i]  = rt[i + 3];
                vpp[i] = vp[i] * vp[i];
                vtt[i] = vt[i] * vt[i];
                vpt[i] = vp[i] * vt[i];
            }
            #pragma unroll
            for (int j = 0; j < KS; ++j) {
                const float wj = wt[j];
                #pragma unroll
                for (int k = 0; k < 4; ++k) {
                    oo[0][k] += wj * vp [k + j];
                    oo[1][k] += wj * vt [k + j];
                    oo[2][k] += wj * vpp[k + j];
                    oo[3][k] += wj * vtt[k + j];
                    oo[4][k] += wj * vpt[k + j];
                }
            }
        }
        s_p [rl][c4] = make_uint2(bf16pair(oo[0][0], oo[0][1]), bf16pair(oo[0][2], oo[0][3]));
        s_t [rl][c4] = make_uint2(bf16pair(oo[1][0], oo[1][1]), bf16pair(oo[1][2], oo[1][3]));
        s_pp[rl][c4] = make_uint2(bf16pair(oo[2][0], oo[2][1]), bf16pair(oo[2][2], oo[2][3]));
        s_tt[rl][c4] = make_uint2(bf16pair(oo[3][0], oo[3][1]), bf16pair(oo[3][2], oo[3][3]));
        s_pt[rl][c4] = make_uint2(bf16pair(oo[4][0], oo[4][1]), bf16pair(oo[4][2], oo[4][3]));
    }
    __syncthreads();

    // ---- Phase 2: vertical 11-tap conv, 2 rows x 4 cols per thread,
    // packed-f32 accumulation (v_pk_fma_f32) ----
    const int c4  = tid & 15;
    const int rr0 = (tid >> 4) * 2;   // output rows rr0, rr0+1

    f32x2 A0[5][2], A1[5][2];         // [array][col-pair half]
    #pragma unroll
    for (int a = 0; a < 5; ++a) {
        A0[a][0] = (f32x2)(0.f); A0[a][1] = (f32x2)(0.f);
        A1[a][0] = (f32x2)(0.f); A1[a][1] = (f32x2)(0.f);
    }
    #pragma unroll
    for (int j = 0; j < 12; ++j) {
        uint2 u[5];
        u[0] = s_p [rr0 + j][c4];
        u[1] = s_t [rr0 + j][c4];
        u[2] = s_pp[rr0 + j][c4];
        u[3] = s_tt[rr0 + j][c4];
        u[4] = s_pt[rr0 + j][c4];
        f32x2 lo[5], hi[5];
        #pragma unroll
        for (int a = 0; a < 5; ++a) { lo[a] = up2(u[a].x); hi[a] = up2(u[a].y); }
        if (j < 11) {
            const float w = wt[j];
            #pragma unroll
            for (int a = 0; a < 5; ++a) { A0[a][0] += w * lo[a]; A0[a][1] += w * hi[a]; }
        }
        if (j >= 1) {
            const float w = wt[j - 1];
            #pragma unroll
            for (int a = 0; a < 5; ++a) { A1[a][0] += w * lo[a]; A1[a][1] += w * hi[a]; }
        }
    }
    float lsum = 0.f;
    lsum += ssim2(A0[0][0], A0[1][0], A0[2][0], A0[3][0], A0[4][0]);
    lsum += ssim2(A0[0][1], A0[1][1], A0[2][1], A0[3][1], A0[4][1]);
    lsum += ssim2(A1[0][0], A1[1][0], A1[2][0], A1[3][0], A1[4][0]);
    lsum += ssim2(A1[0][1], A1[1][1], A1[2][1], A1[3][1], A1[4][1]);

    // ---- Block reduction -> one double atomic per block ----
    #pragma unroll
    for (int off = 32; off > 0; off >>= 1)
        lsum += __shfl_down(lsum, off, 64);
    const int wave = tid >> 6;
    const int lane = tid & 63;
    if (lane == 0) wave_part[wave] = lsum;
    __syncthreads();
    if (tid == 0) {
        const float bs = wave_part[0] + wave_part[1] + wave_part[2] + wave_part[3];
        atomicAdd(acc, (double)bs);
    }
}

__global__ void ssim_final(const double* __restrict__ acc, float* __restrict__ out) {
    if (threadIdx.x == 0) {
        const double n = (double)N_IMG * (double)IMG_H * (double)IMG_W;
        out[0] = (float)(1.0 - acc[0] / n);
    }
}

extern "C" void kernel_launch(void* const* d_in, const int* in_sizes, int n_in,
                              void* d_out, int out_size, void* d_ws, size_t ws_size,
                              hipStream_t stream) {
    const float* pred = (const float*)d_in[0];
    const float* targ = (const float*)d_in[1];
    float* out  = (float*)d_out;
    double* acc = (double*)d_ws;

    hipLaunchKernelGGL(ssim_zero_acc, dim3(1), dim3(1), 0, stream, acc);
    dim3 grid(IMG_W / TILE_W, IMG_H / TILE_H, N_IMG);   // (8, 16, 48)
    hipLaunchKernelGGL(ssim_main, grid, dim3(256), 0, stream, pred, targ, acc);
    hipLaunchKernelGGL(ssim_final, dim3(1), dim3(1), 0, stream, acc, out);
}

// Round 8
// 182.504 us; speedup vs baseline: 1.1321x; 1.0590x over previous
//
#include <hip/hip_runtime.h>

#define IMG_W 512
#define IMG_H 512
#define N_IMG 48            // 16 batch * 3 channels
#define TILE_W 64
#define TILE_H 32
#define RAD 5
#define XROWS 48            // 42 halo rows padded to 3 m-tiles of 16
#define XCOLS 80            // cols col0-8 .. col0+71 (16B-aligned float4 staging)
#define YTROWS 48           // transposed hconv buffer: rows per col
#define NBX (IMG_W / TILE_W)   // 8
#define NBY (IMG_H / TILE_H)   // 16

typedef float f32x4v __attribute__((ext_vector_type(4)));
typedef short bf16x8 __attribute__((ext_vector_type(8)));

__global__ void ssim_zero_acc(double* acc) {
    if (threadIdx.x == 0) acc[0] = 0.0;
}

// RNE round fp32 -> bf16 bits
__device__ inline short bf16r(float a) {
    unsigned int u = __float_as_uint(a);
    u = (u + 0x7fffu + ((u >> 16) & 1u)) >> 16;
    return (short)u;
}
__device__ inline unsigned int bf16pair(float a, float b) {
    return (unsigned int)(unsigned short)bf16r(a)
         | ((unsigned int)(unsigned short)bf16r(b) << 16);
}

// NOTE 1 (R3/R4 vs R5): NO __threadfence / fold-in finalize. Per-block
// agent-scope fence forces XCD-L2 writeback 6144x/dispatch; halo re-reads
// fall L2->L3 and dur triples. Separate finalize kernel is free.
// NOTE 2 (R6): launch_bounds min-waves stays 4. (256,6) made the allocator
// spill ~67MB to scratch. LDS (38.4KB) caps us at 4 blocks/CU anyway.
// NOTE 3 (R8): both 11-tap convs run on MFMA: data in A (k-contiguous b128
// from LDS), banded Gaussian weights in B (B[k][n]=wt[k-n-c], built from
// expf in-register). C/D layout (col=lane&15,row=q*4+reg) writes 4
// row-consecutive values of one col = b64 into transposed Y -> the
// transpose the V-pass A-fragments need is free.
__global__ __launch_bounds__(256, 4)
void ssim_main(const float* __restrict__ pred, const float* __restrict__ targ,
               double* __restrict__ acc)
{
    __shared__ __align__(16) union {
        unsigned short X [5][XROWS][XCOLS];    // [arr][halo row][ci], ci = imgcol - col0 + 8
        unsigned short YT[5][TILE_W][YTROWS];  // [arr][tile col][halo row]
    } sh;
    __shared__ float wave_part[4];

    const int tid  = threadIdx.x;
    const int lane = tid & 63;
    const int wv   = tid >> 6;     // wave 0..3
    const int n15  = lane & 15;
    const int q    = lane >> 4;    // 0..3

    // Gaussian normalization (sigma=1.5): ssum = sum_{i=0..10} exp(-(i-5)^2/4.5)
    float ssum = 0.f;
    #pragma unroll
    for (int i = 0; i < 11; ++i) {
        const float d = (float)(i - 5);
        ssum += expf(-d * d / 4.5f);
    }
    const float inv_ssum = 1.f / ssum;

    // B fragments (weights), one per conv. Lane holds B[k][n], n=lane&15,
    // k=q*8+j. Hconv: tap d = k - n - 3 (k-window starts 3 cols left of the
    // leftmost tap of out col 0). Vconv: d = k - n (n-tile1 reuses the same
    // fragment via a K-window starting at row 16).
    bf16x8 Bh, Bv;
    #pragma unroll
    for (int j = 0; j < 8; ++j) {
        const int k = q * 8 + j;
        {
            const int d = k - n15 - 3;
            const float x = (float)(d - 5);
            const float v = expf(-x * x / 4.5f) * inv_ssum;
            Bh[j] = bf16r((d >= 0 && d <= 10) ? v : 0.f);
        }
        {
            const int d = k - n15;
            const float x = (float)(d - 5);
            const float v = expf(-x * x / 4.5f) * inv_ssum;
            Bv[j] = bf16r((d >= 0 && d <= 10) ? v : 0.f);
        }
    }

    const int col0 = blockIdx.x * TILE_W;
    const int row0 = blockIdx.y * TILE_H;
    const bool edge = (blockIdx.x == 0) || (blockIdx.x == NBX - 1);
    const long img = blockIdx.z;
    const float* __restrict__ p = pred + img * (long)(IMG_H * IMG_W);
    const float* __restrict__ t = targ + img * (long)(IMG_H * IMG_W);

    // ---- Phase 0: stage {p,t,pp,tt,pt} bf16 into X, zero outside image.
    // Every element of X is written (finite) — MFMA reads the full [48][80]
    // footprint and 0-weight x Inf/NaN garbage would poison accumulators.
    for (int idx = tid; idx < XROWS * 20; idx += 256) {   // 960 items
        const int r = idx / 20;
        const int g = idx - r * 20;
        const int gr  = row0 - RAD + r;
        const int gcb = col0 - 8 + 4 * g;
        float pv[4] = {0.f, 0.f, 0.f, 0.f};
        float tv[4] = {0.f, 0.f, 0.f, 0.f};
        if (gr >= 0 && gr < IMG_H) {
            const float* __restrict__ prow = p + (long)gr * IMG_W;
            const float* __restrict__ trow = t + (long)gr * IMG_W;
            if (!edge || (gcb >= 0 && gcb + 4 <= IMG_W)) {
                const float4 a = *(const float4*)&prow[gcb];
                const float4 b = *(const float4*)&trow[gcb];
                pv[0] = a.x; pv[1] = a.y; pv[2] = a.z; pv[3] = a.w;
                tv[0] = b.x; tv[1] = b.y; tv[2] = b.z; tv[3] = b.w;
            } else {
                #pragma unroll
                for (int e = 0; e < 4; ++e) {
                    const int c = gcb + e;
                    if (c >= 0 && c < IMG_W) { pv[e] = prow[c]; tv[e] = trow[c]; }
                }
            }
        }
        const uint2 uP  = make_uint2(bf16pair(pv[0], pv[1]), bf16pair(pv[2], pv[3]));
        const uint2 uT  = make_uint2(bf16pair(tv[0], tv[1]), bf16pair(tv[2], tv[3]));
        const uint2 uPP = make_uint2(bf16pair(pv[0]*pv[0], pv[1]*pv[1]),
                                     bf16pair(pv[2]*pv[2], pv[3]*pv[3]));
        const uint2 uTT = make_uint2(bf16pair(tv[0]*tv[0], tv[1]*tv[1]),
                                     bf16pair(tv[2]*tv[2], tv[3]*tv[3]));
        const uint2 uPT = make_uint2(bf16pair(pv[0]*tv[0], pv[1]*tv[1]),
                                     bf16pair(pv[2]*tv[2], pv[3]*tv[3]));
        *(uint2*)&sh.X[0][r][4 * g] = uP;
        *(uint2*)&sh.X[1][r][4 * g] = uT;
        *(uint2*)&sh.X[2][r][4 * g] = uPP;
        *(uint2*)&sh.X[3][r][4 * g] = uTT;
        *(uint2*)&sh.X[4][r][4 * g] = uPT;
    }
    __syncthreads();

    // ---- MFMA pass 1: horizontal conv. Wave wv owns out-col tile wv.
    // A[m][k] = X[mt*16+m][wv*16+k]; D[m][n] = Y[mt*16+m][outcol wv*16+n].
    // Lane gets 4 row-consecutive values of one col -> pack -> held in regs
    // until X is fully consumed (barrier), then b64 into transposed YT.
    uint2 yreg[15];
    {
        const f32x4v cz = {0.f, 0.f, 0.f, 0.f};
        int i = 0;
        #pragma unroll
        for (int a = 0; a < 5; ++a) {
            #pragma unroll
            for (int mt = 0; mt < 3; ++mt) {
                const bf16x8 A = *(const bf16x8*)&sh.X[a][mt * 16 + n15][wv * 16 + 8 * q];
                const f32x4v c = __builtin_amdgcn_mfma_f32_16x16x32_bf16(A, Bh, cz, 0, 0, 0);
                yreg[i++] = make_uint2(bf16pair(c[0], c[1]), bf16pair(c[2], c[3]));
            }
        }
    }
    __syncthreads();   // all X reads complete; union space becomes YT
    {
        int i = 0;
        #pragma unroll
        for (int a = 0; a < 5; ++a)
            #pragma unroll
            for (int mt = 0; mt < 3; ++mt)
                *(uint2*)&sh.YT[a][wv * 16 + n15][mt * 16 + 4 * q] = yreg[i++];
    }
    __syncthreads();

    // ---- MFMA pass 2: vertical conv. Wave wv owns image-col tile wv.
    // A[m][k] = YT[col wv*16+m][nt*16+k] (K-window rows nt*16..+31, band fits
    // for both n-tiles with the same Bv). D[m][n]: lane gets out row
    // nt*16+n15, cols wv*16+q*4+{0..3} for the 5 arrays.
    f32x4v accv[2][5];
    {
        const f32x4v cz = {0.f, 0.f, 0.f, 0.f};
        #pragma unroll
        for (int nt = 0; nt < 2; ++nt)
            #pragma unroll
            for (int a = 0; a < 5; ++a) {
                const bf16x8 A = *(const bf16x8*)&sh.YT[a][wv * 16 + n15][nt * 16 + 8 * q];
                accv[nt][a] = __builtin_amdgcn_mfma_f32_16x16x32_bf16(A, Bv, cz, 0, 0, 0);
            }
    }

    // ---- SSIM on 8 pixels/lane (2 n-tiles x 4 cols), fp32 ----
    float lsum = 0.f;
    #pragma unroll
    for (int nt = 0; nt < 2; ++nt) {
        const f32x4v m1 = accv[nt][0], m2 = accv[nt][1];
        const f32x4v epp = accv[nt][2], ett = accv[nt][3], ept = accv[nt][4];
        const f32x4v m1s = m1 * m1, m2s = m2 * m2, m12 = m1 * m2;
        const f32x4v num = (2.f * m12 + 1e-4f) * (2.f * (ept - m12) + 9e-4f);
        const f32x4v den = (m1s + m2s + 1e-4f) * ((epp - m1s) + (ett - m2s) + 9e-4f);
        lsum += num[0] * __builtin_amdgcn_rcpf(den[0]);
        lsum += num[1] * __builtin_amdgcn_rcpf(den[1]);
        lsum += num[2] * __builtin_amdgcn_rcpf(den[2]);
        lsum += num[3] * __builtin_amdgcn_rcpf(den[3]);
    }

    // ---- Block reduction -> one double atomic per block ----
    #pragma unroll
    for (int off = 32; off > 0; off >>= 1)
        lsum += __shfl_down(lsum, off, 64);
    if (lane == 0) wave_part[wv] = lsum;
    __syncthreads();
    if (tid == 0) {
        const float bs = wave_part[0] + wave_part[1] + wave_part[2] + wave_part[3];
        atomicAdd(acc, (double)bs);
    }
}

__global__ void ssim_final(const double* __restrict__ acc, float* __restrict__ out) {
    if (threadIdx.x == 0) {
        const double n = (double)N_IMG * (double)IMG_H * (double)IMG_W;
        out[0] = (float)(1.0 - acc[0] / n);
    }
}

extern "C" void kernel_launch(void* const* d_in, const int* in_sizes, int n_in,
                              void* d_out, int out_size, void* d_ws, size_t ws_size,
                              hipStream_t stream) {
    const float* pred = (const float*)d_in[0];
    const float* targ = (const float*)d_in[1];
    float* out  = (float*)d_out;
    double* acc = (double*)d_ws;

    hipLaunchKernelGGL(ssim_zero_acc, dim3(1), dim3(1), 0, stream, acc);
    dim3 grid(NBX, NBY, N_IMG);   // (8, 16, 48)
    hipLaunchKernelGGL(ssim_main, grid, dim3(256), 0, stream, pred, targ, acc);
    hipLaunchKernelGGL(ssim_final, dim3(1), dim3(1), 0, stream, acc, out);
}